// Round 1
// baseline (87.671 us; speedup 1.0000x reference)
//
#include <hip/hip_runtime.h>
#include <math.h>

// Fused: h=relu(x@W1+b1) -> reduced=tanh(h@W2+b2) -> 4-qubit circuit -> head.
// Grid 256 x 256 threads. Block: 64 rows x 64 cols, wave-private K-split
// (wave w owns k-quarter w*16..+16 of each 64-wide K tile) => barrier-free
// GEMM main loop. Double-buffered LDS (2x16KB A + 2x16KB B = 64KB), reused
// as the 4x[64c][64s] partial buffer for the fused tail.

#define NKT 20  // 1280 / 64

#define APPLY_RY(BIT, C, S)                                                  \
  { _Pragma("unroll")                                                        \
    for (int i = 0; i < 16; ++i) {                                           \
      if (!(i & (BIT))) {                                                    \
        const int j = i | (BIT);                                             \
        float ar = re[i], ai = im[i], br = re[j], bi = im[j];                \
        re[i] = fmaf((C), ar, -(S) * br);                                    \
        im[i] = fmaf((C), ai, -(S) * bi);                                    \
        re[j] = fmaf((S), ar, (C) * br);                                     \
        im[j] = fmaf((S), ai, (C) * bi);                                     \
      }                                                                      \
    } }

// rz(t) = diag(e^{-it/2}, e^{+it/2}); C=cos(t/2), S=sin(t/2)
#define APPLY_RZ(BIT, C, S)                                                  \
  { _Pragma("unroll")                                                        \
    for (int i = 0; i < 16; ++i) {                                           \
      float vr = re[i], vi = im[i];                                          \
      if (!(i & (BIT))) { re[i] = fmaf((C), vr, (S) * vi);                   \
                          im[i] = fmaf((C), vi, -(S) * vr); }                \
      else              { re[i] = fmaf((C), vr, -(S) * vi);                  \
                          im[i] = fmaf((C), vi, (S) * vr); }                 \
    } }

#define APPLY_CNOT(CB, TB)                                                   \
  { _Pragma("unroll")                                                        \
    for (int i = 0; i < 16; ++i) {                                           \
      if ((i & (CB)) && !(i & (TB))) {                                       \
        const int j = i | (TB);                                              \
        float t = re[i]; re[i] = re[j]; re[j] = t;                           \
        t = im[i]; im[i] = im[j]; im[j] = t;                                 \
      }                                                                      \
    } }

__global__ __launch_bounds__(256) void qfc_fused(
    const float* __restrict__ x,    // [16384,1280]
    const float* __restrict__ W1,   // [1280,64]
    const float* __restrict__ b1,   // [64]
    const float* __restrict__ W2,   // [64,4]
    const float* __restrict__ b2,   // [4]
    const float* __restrict__ qw,   // [3,4,2]
    const float* __restrict__ Wc1,  // [8,16]
    const float* __restrict__ bc1,  // [16]
    const float* __restrict__ Wc2,  // [16]
    const float* __restrict__ bc2,  // [1]
    float* __restrict__ out)        // [16384]
{
  // LDS layout (floats):
  // [0,4096)      As buf0   [k 0..63][row 0..63]
  // [4096,8192)   As buf1
  // [8192,12288)  Bs buf0   [k 0..63][col 0..63]
  // [12288,16384) Bs buf1
  // Epilogue reuse: part[w][c][s] at w*4096 + c*64 + s
  __shared__ float lds[16384];

  const int tid  = threadIdx.x;
  const int lane = tid & 63;
  const int wv   = tid >> 6;   // wave id == k-quarter owner
  const int rg   = lane >> 3;  // row group (8 rows)
  const int cg   = lane & 7;   // col group (8 cols)
  const int r0   = blockIdx.x * 64;

  float acc[8][8];
#pragma unroll
  for (int i = 0; i < 8; ++i)
#pragma unroll
    for (int j = 0; j < 8; ++j) acc[i][j] = 0.f;

  const float* xrow  = x + (size_t)(r0 + lane) * 1280 + wv * 16;
  const int    aBase = wv * 1024;         // (wv*16)*64 within As buffer
  const int    bBase = 8192 + wv * 1024;  // within Bs region

  float4 a_st[4], b_st[4];

  auto issue_loads = [&](int kt) {
    const float* ap = xrow + kt * 64;
#pragma unroll
    for (int i = 0; i < 4; ++i) a_st[i] = *(const float4*)(ap + i * 4);
    const float* bp = W1 + kt * 4096 + wv * 1024 + lane * 4;
#pragma unroll
    for (int i = 0; i < 4; ++i) b_st[i] = *(const float4*)(bp + i * 256);
  };

  auto write_stage = [&](int buf) {
    // A transposed: As[k][row]; this wave writes its 16 k's, row = lane
    float* A = &lds[buf * 4096 + aBase];
#pragma unroll
    for (int i = 0; i < 4; ++i) {
      float* p = A + i * 256 + lane;
      p[0] = a_st[i].x; p[64] = a_st[i].y; p[128] = a_st[i].z; p[192] = a_st[i].w;
    }
    // B linear copy (global row-major [k][64] == LDS layout)
    float* Bp = &lds[buf * 4096 + bBase + lane * 4];
#pragma unroll
    for (int i = 0; i < 4; ++i) *(float4*)(Bp + i * 256) = b_st[i];
  };

  auto compute_tile = [&](int buf) {
#pragma unroll
    for (int m = 0; m < 16; ++m) {
      const float* Ak = &lds[buf * 4096 + aBase + m * 64];
      const float* Bk = &lds[buf * 4096 + bBase + m * 64];
      const float4 a0 = *(const float4*)(Ak + rg * 8);
      const float4 a1 = *(const float4*)(Ak + rg * 8 + 4);
      const float4 c0 = *(const float4*)(Bk + cg * 8);
      const float4 c1 = *(const float4*)(Bk + cg * 8 + 4);
      const float av[8] = {a0.x, a0.y, a0.z, a0.w, a1.x, a1.y, a1.z, a1.w};
      const float bv[8] = {c0.x, c0.y, c0.z, c0.w, c1.x, c1.y, c1.z, c1.w};
#pragma unroll
      for (int i = 0; i < 8; ++i)
#pragma unroll
        for (int j = 0; j < 8; ++j)
          acc[i][j] = fmaf(av[i], bv[j], acc[i][j]);
    }
  };

  // Barrier-free, wave-self-paced double-buffered K loop
  issue_loads(0);
  write_stage(0);
  for (int kt = 0; kt < NKT; ++kt) {
    const int buf = kt & 1;
    if (kt + 1 < NKT) issue_loads(kt + 1);
    compute_tile(buf);
    if (kt + 1 < NKT) write_stage(buf ^ 1);
  }

  // ---- hand off k-split partials: part[w][c][s] = w*4096 + c*64 + s ----
  __syncthreads();
#pragma unroll
  for (int j = 0; j < 8; ++j) {
    const int c = cg * 8 + j;
    float* p = &lds[wv * 4096 + c * 64 + rg * 8];
    *(float4*)p       = make_float4(acc[0][j], acc[1][j], acc[2][j], acc[3][j]);
    *(float4*)(p + 4) = make_float4(acc[4][j], acc[5][j], acc[6][j], acc[7][j]);
  }
  __syncthreads();

  // ---- fused tail: 4 threads per sample ----
  const int s  = tid >> 2;  // sample within tile (0..63)
  const int cq = tid & 3;   // c-quarter (16 cols each)

  float h4[4] = {0.f, 0.f, 0.f, 0.f};
#pragma unroll
  for (int cc = 0; cc < 16; ++cc) {
    const int c = cq * 16 + cc;
    const int o = c * 64 + s;
    float p  = (lds[o] + lds[4096 + o]) + (lds[8192 + o] + lds[12288 + o]);
    float hv = fmaxf(p + b1[c], 0.f);
    const float4 w2 = *(const float4*)(W2 + c * 4);
    h4[0] = fmaf(hv, w2.x, h4[0]);
    h4[1] = fmaf(hv, w2.y, h4[1]);
    h4[2] = fmaf(hv, w2.z, h4[2]);
    h4[3] = fmaf(hv, w2.w, h4[3]);
  }
#pragma unroll
  for (int k = 0; k < 4; ++k) {
    h4[k] += __shfl_xor(h4[k], 1);
    h4[k] += __shfl_xor(h4[k], 2);
  }

  float red[4];
#pragma unroll
  for (int k = 0; k < 4; ++k) red[k] = tanhf(h4[k] + b2[k]);

  // ---- 4-qubit statevector, fully unrolled in registers ----
  // wire w <-> BIT 8>>w (axis 1+w of [B,2,2,2,2]); state idx = q0*8+q1*4+q2*2+q3
  float re[16], im[16];
#pragma unroll
  for (int i = 0; i < 16; ++i) { re[i] = 0.f; im[i] = 0.f; }
  re[0] = 1.f;

  {
    float s0, c0; sincosf(0.5f * red[0], &s0, &c0); APPLY_RY(8, c0, s0);
    float s1, c1; sincosf(0.5f * red[1], &s1, &c1); APPLY_RY(4, c1, s1);
    float s2, c2; sincosf(0.5f * red[2], &s2, &c2); APPLY_RY(2, c2, s2);
    float s3, c3; sincosf(0.5f * red[3], &s3, &c3); APPLY_RY(1, c3, s3);
  }

  for (int l = 0; l < 3; ++l) {
    const float* ql = qw + l * 8;
    { float sn, cn; sincosf(0.5f * ql[0], &sn, &cn); APPLY_RY(8, cn, sn); }
    { float sn, cn; sincosf(0.5f * ql[1], &sn, &cn); APPLY_RZ(8, cn, sn); }
    { float sn, cn; sincosf(0.5f * ql[2], &sn, &cn); APPLY_RY(4, cn, sn); }
    { float sn, cn; sincosf(0.5f * ql[3], &sn, &cn); APPLY_RZ(4, cn, sn); }
    { float sn, cn; sincosf(0.5f * ql[4], &sn, &cn); APPLY_RY(2, cn, sn); }
    { float sn, cn; sincosf(0.5f * ql[5], &sn, &cn); APPLY_RZ(2, cn, sn); }
    { float sn, cn; sincosf(0.5f * ql[6], &sn, &cn); APPLY_RY(1, cn, sn); }
    { float sn, cn; sincosf(0.5f * ql[7], &sn, &cn); APPLY_RZ(1, cn, sn); }
    APPLY_CNOT(8, 4);  // cnot(0,1)
    APPLY_CNOT(4, 2);  // cnot(1,2)
    APPLY_CNOT(2, 1);  // cnot(2,3)
    APPLY_CNOT(1, 8);  // cnot(3,0)
  }

  float q0 = 0.f, q1 = 0.f, q2 = 0.f, q3 = 0.f;
#pragma unroll
  for (int i = 0; i < 16; ++i) {
    const float pr = fmaf(re[i], re[i], im[i] * im[i]);
    q0 += (i & 8) ? -pr : pr;
    q1 += (i & 4) ? -pr : pr;
    q2 += (i & 2) ? -pr : pr;
    q3 += (i & 1) ? -pr : pr;
  }

  // ---- head: relu(comb @ Wc1 + bc1) @ Wc2 + bc2 ----
  float logit = bc2[0];
#pragma unroll
  for (int j = 0; j < 16; ++j) {
    float a = bc1[j];
    a = fmaf(red[0], Wc1[j],        a);
    a = fmaf(red[1], Wc1[16 + j],   a);
    a = fmaf(red[2], Wc1[32 + j],   a);
    a = fmaf(red[3], Wc1[48 + j],   a);
    a = fmaf(q0,     Wc1[64 + j],   a);
    a = fmaf(q1,     Wc1[80 + j],   a);
    a = fmaf(q2,     Wc1[96 + j],   a);
    a = fmaf(q3,     Wc1[112 + j],  a);
    logit = fmaf(fmaxf(a, 0.f), Wc2[j], logit);
  }

  if (cq == 0) out[r0 + s] = logit;
}

extern "C" void kernel_launch(void* const* d_in, const int* in_sizes, int n_in,
                              void* d_out, int out_size, void* d_ws, size_t ws_size,
                              hipStream_t stream) {
  const float* x   = (const float*)d_in[0];
  const float* W1  = (const float*)d_in[1];
  const float* b1  = (const float*)d_in[2];
  const float* W2  = (const float*)d_in[3];
  const float* b2  = (const float*)d_in[4];
  const float* qw  = (const float*)d_in[5];
  const float* Wc1 = (const float*)d_in[6];
  const float* bc1 = (const float*)d_in[7];
  const float* Wc2 = (const float*)d_in[8];
  const float* bc2 = (const float*)d_in[9];

  qfc_fused<<<dim3(256), dim3(256), 0, stream>>>(
      x, W1, b1, W2, b2, qw, Wc1, bc1, Wc2, bc2, (float*)d_out);
}